// Round 5
// baseline (560.387 us; speedup 1.0000x reference)
//
#include <hip/hip_runtime.h>
#include <hip/hip_bf16.h>
#include <math.h>

// Problem constants
#define N_DEST 16000   // B * D_CNT
#define KN     32      // neighbors per dest
#define HIDN   128
#define NH     4
#define HD     32
#define SRCD   64
#define EDGED  16
#define XD     80      // SRCD + EDGED
#define XDP    96      // XD padded to 3 K-tiles of 32
#define SXP    104     // sx LDS row stride (96 + 8)
#define SNP    136     // 128-wide LDS row stride (128 + 8)
#define G      2       // dest nodes per block

typedef __attribute__((ext_vector_type(8))) short frag8;   // 8 bf16 (4 VGPR)
typedef __attribute__((ext_vector_type(4))) float f32x4;

// tanh-form GELU (|diff vs exact erf-gelu| <= ~2e-3), ~7 VALU ops
__device__ __forceinline__ float gelu_tanh(float x) {
    float t = x * x;
    float m = fmaf(t, -0.07135481627f, -1.5957691216f);   // -(2u)/x
    float e = __expf(x * m);                              // e^{-2u}
    return __fdividef(x, 1.0f + e);                       // x * sigmoid(2u)
}
__device__ __forceinline__ unsigned short f2bf(float f) {
    __hip_bfloat16 h = __float2bfloat16(f);
    union { __hip_bfloat16 h; unsigned short u; } c; c.h = h; return c.u;
}
__device__ __forceinline__ unsigned int pk2bf(float x, float y) {
    __hip_bfloat162 h2 = __float22bfloat162_rn(make_float2(x, y));
    union { __hip_bfloat162 h; unsigned int u; } c; c.h = h2; return c.u;
}
__device__ __forceinline__ float bf2f(unsigned short h) {
    union { unsigned int u; float f; } c; c.u = ((unsigned int)h) << 16;
    return c.f;
}

// ---- prep: convert W_src (pad K 80->96) and Wqkv K/V rows to bf16 in d_ws ----
__global__ void prep_weights(const float* __restrict__ W_src,
                             const float* __restrict__ Wqkv,
                             unsigned short* __restrict__ ws) {
    int i = blockIdx.x * 256 + threadIdx.x;
    if (i < 128 * XDP) {
        int r = i / XDP, c = i - r * XDP;
        ws[i] = f2bf(c < XD ? W_src[r * XD + c] : 0.0f);
    } else {
        int j = i - 128 * XDP;           // < 256*128
        int r = j >> 7, c = j & 127;
        ws[i] = f2bf(Wqkv[(128 + r) * HIDN + c]);
    }
}

__global__ __launch_bounds__(256, 4) void fused_gat_mfma(
    const float* __restrict__ src,    // (16000, 64)
    const float* __restrict__ dest,   // (16000, 64)
    const int*   __restrict__ adj,    // (32, 16000)
    const int*   __restrict__ mask,   // (16000, 32)
    const float* __restrict__ edges,  // (32, 16000, 16)
    const float* __restrict__ b_src,  // (128)
    const float* __restrict__ W_dest, // (128, 64)
    const float* __restrict__ b_dest, // (128)
    const float* __restrict__ Wqkv,   // (384, 128) fp32 (Q rows used here)
    const float* __restrict__ bqkv,   // (384)
    const float* __restrict__ Wo,     // (128, 128)
    const float* __restrict__ bo,     // (128)
    const float* __restrict__ ln_g,
    const float* __restrict__ ln_b,
    const unsigned short* __restrict__ Wsb,   // bf16 128 x 96
    const unsigned short* __restrict__ Wkvb,  // bf16 256 x 128 (K rows 0-127, V 128-255)
    float* __restrict__ out)
{
    const int tid  = threadIdx.x;
    const int n0   = blockIdx.x * G;
    const int w    = tid >> 6;        // wave id 0..3
    const int lane = tid & 63;
    const int lg   = lane >> 4;       // 0..3
    const int lm   = lane & 15;       // 0..15

    // sx dead after GEMM-D; V written in GEMM-E phase -> alias them.
    __shared__ __align__(16) union {
        unsigned short sx[G * KN][SXP];     // 13.0 KB
        unsigned short v [G * KN][SNP];     // 17.0 KB
    } u;
    __shared__ __align__(16) unsigned short s_sin[G * KN][SNP];   // 17.0 KB
    __shared__ __align__(16) float s_dest[G][HIDN];
    __shared__ __align__(16) float s_q[G][HIDN];
    __shared__ __align__(16) float s_attn[G][NH][KN];
    __shared__ __align__(16) float s_ctx[G][HIDN];
    __shared__ float s_red[4][2];
    __shared__ unsigned s_mask[G];    // bit kk set => masked out

    // ---------------- phase 0: mask ballot + gather (bf16) + dest_in ----------
    if (w == 0) {
        const int g = lane >> 5, kk = lane & 31;
        unsigned long long bal = __ballot(mask[(n0 + g) * KN + kk] != 0);
        if (lane == 0) { s_mask[0] = (unsigned)bal; s_mask[1] = (unsigned)(bal >> 32); }
    }
    {
        const int row = tid >> 2;            // 0..63  (g*32 + kk)
        const int part = tid & 3;
        const int g = row >> 5, kk = row & 31;
        const int a_adj = adj[kk * N_DEST + (n0 + g)];
        const float* srow = (a_adj == 0) ? nullptr : src + (size_t)(a_adj - 1) * SRCD;
        if (part < 3) {
            const int c0 = part * 20;        // cols [c0, c0+20), pure src
            #pragma unroll
            for (int q = 0; q < 5; ++q) {
                float4 f = srow ? *(const float4*)(srow + c0 + q * 4)
                                : make_float4(0.f, 0.f, 0.f, 0.f);
                *(unsigned int*)&u.sx[row][c0 + q * 4]     = pk2bf(f.x, f.y);
                *(unsigned int*)&u.sx[row][c0 + q * 4 + 2] = pk2bf(f.z, f.w);
            }
        } else {
            float4 f = srow ? *(const float4*)(srow + 60)
                            : make_float4(0.f, 0.f, 0.f, 0.f);
            *(unsigned int*)&u.sx[row][60] = pk2bf(f.x, f.y);
            *(unsigned int*)&u.sx[row][62] = pk2bf(f.z, f.w);
            const float4* ep = (const float4*)(edges + ((size_t)kk * N_DEST + (n0 + g)) * EDGED);
            #pragma unroll
            for (int q = 0; q < 4; ++q) {
                float4 e = ep[q];
                *(unsigned int*)&u.sx[row][64 + q * 4]     = pk2bf(e.x, e.y);
                *(unsigned int*)&u.sx[row][64 + q * 4 + 2] = pk2bf(e.z, e.w);
            }
            #pragma unroll
            for (int c = 80; c < XDP; c += 2) *(unsigned int*)&u.sx[row][c] = 0u;
        }
    }
    {
        const int g = tid >> 7, j = tid & 127;
        float acc = b_dest[j];
        const float4* w4 = (const float4*)(W_dest + j * SRCD);
        const float4* x4 = (const float4*)(dest + (size_t)(n0 + g) * SRCD);
        #pragma unroll
        for (int c = 0; c < SRCD / 4; ++c) {
            float4 wv = w4[c]; float4 x = x4[c];
            acc = fmaf(wv.x, x.x, acc); acc = fmaf(wv.y, x.y, acc);
            acc = fmaf(wv.z, x.z, acc); acc = fmaf(wv.w, x.w, acc);
        }
        s_dest[g][j] = gelu_tanh(acc);
    }
    __syncthreads();

    // ---------------- phase 1: q projection + GEMM-D -> gelu -> s_sin ----------
    {
        const int g = tid >> 7, j = tid & 127;
        float acc = bqkv[j];
        const float4* w4 = (const float4*)(Wqkv + (size_t)j * HIDN);
        const float4* x4 = (const float4*)s_dest[g];
        #pragma unroll
        for (int c = 0; c < HIDN / 4; ++c) {
            float4 wv = w4[c]; float4 x = x4[c];
            acc = fmaf(wv.x, x.x, acc); acc = fmaf(wv.y, x.y, acc);
            acc = fmaf(wv.z, x.z, acc); acc = fmaf(wv.w, x.w, acc);
        }
        s_q[g][j] = acc * 0.17677669529663688110f;   // 1/sqrt(32)
    }
    {
        const int row0 = (w >> 1) * 32, col0 = (w & 1) * 64;
        f32x4 acc[2][4];
        #pragma unroll
        for (int c = 0; c < 4; ++c) {
            float bias = b_src[col0 + c * 16 + lm];
            #pragma unroll
            for (int r = 0; r < 2; ++r) acc[r][c] = (f32x4){bias, bias, bias, bias};
        }
        #pragma unroll
        for (int kt = 0; kt < 3; ++kt) {
            frag8 a[2], b[4];
            #pragma unroll
            for (int r = 0; r < 2; ++r)
                a[r] = *(const frag8*)&u.sx[row0 + r * 16 + lm][kt * 32 + lg * 8];
            #pragma unroll
            for (int c = 0; c < 4; ++c)
                b[c] = *(const frag8*)(Wsb + (size_t)(col0 + c * 16 + lm) * XDP + kt * 32 + lg * 8);
            #pragma unroll
            for (int r = 0; r < 2; ++r)
                #pragma unroll
                for (int c = 0; c < 4; ++c)
                    acc[r][c] = __builtin_amdgcn_mfma_f32_16x16x32_bf16(a[r], b[c], acc[r][c], 0, 0, 0);
        }
        #pragma unroll
        for (int r = 0; r < 2; ++r)
            #pragma unroll
            for (int c = 0; c < 4; ++c)
                #pragma unroll
                for (int e = 0; e < 4; ++e)
                    s_sin[row0 + r * 16 + lg * 4 + e][col0 + c * 16 + lm] =
                        f2bf(gelu_tanh(acc[r][c][e]));
    }
    __syncthreads();

    // ---------------- phase 2: GEMM-E in two 32-col halves --------------------
    // waves 0,1: K cols; half h2 == head 2w+h2 -> in-register masked softmax -> s_attn
    // waves 2,3: V cols -> bf16 -> u.v  (acc dies in-phase; 32 AGPR peak)
    #pragma unroll 1
    for (int h2 = 0; h2 < 2; ++h2) {
        const int cb = w * 64 + h2 * 32;     // row offset into Wkvb
        f32x4 acc[4][2];
        #pragma unroll
        for (int c = 0; c < 2; ++c) {
            float bias = bqkv[128 + cb + c * 16 + lm];
            #pragma unroll
            for (int r = 0; r < 4; ++r) acc[r][c] = (f32x4){bias, bias, bias, bias};
        }
        #pragma unroll
        for (int kt = 0; kt < 4; ++kt) {
            frag8 a[4], b[2];
            #pragma unroll
            for (int r = 0; r < 4; ++r)
                a[r] = *(const frag8*)&s_sin[r * 16 + lm][kt * 32 + lg * 8];
            #pragma unroll
            for (int c = 0; c < 2; ++c)
                b[c] = *(const frag8*)(Wkvb + (size_t)(cb + c * 16 + lm) * HIDN + kt * 32 + lg * 8);
            #pragma unroll
            for (int r = 0; r < 4; ++r)
                #pragma unroll
                for (int c = 0; c < 2; ++c)
                    acc[r][c] = __builtin_amdgcn_mfma_f32_16x16x32_bf16(a[r], b[c], acc[r][c], 0, 0, 0);
        }
        if (w < 2) {
            const int head = 2 * w + h2;
            float qv[2][2];
            #pragma unroll
            for (int g2 = 0; g2 < 2; ++g2) {
                qv[g2][0] = s_q[g2][cb + lm];
                qv[g2][1] = s_q[g2][cb + 16 + lm];
            }
            float vals[2][8];    // [g2][(r&1)*4 + e], kk = (j>>2)*16 + lg*4 + (j&3)
            #pragma unroll
            for (int r = 0; r < 4; ++r) {
                const int g2 = r >> 1;
                #pragma unroll
                for (int e = 0; e < 4; ++e) {
                    float v = acc[r][0][e] * qv[g2][0] + acc[r][1][e] * qv[g2][1];
                    v += __shfl_xor(v, 1); v += __shfl_xor(v, 2);
                    v += __shfl_xor(v, 4); v += __shfl_xor(v, 8);
                    vals[g2][(r & 1) * 4 + e] = v;
                }
            }
            #pragma unroll
            for (int g2 = 0; g2 < 2; ++g2) {
                const unsigned mw = s_mask[g2];
                const int kkb = lg * 4;
                float m8 = -1e30f;
                #pragma unroll
                for (int j = 0; j < 8; ++j) {
                    const int kk = (j >> 2) * 16 + kkb + (j & 3);
                    if ((mw >> kk) & 1u) vals[g2][j] = -1e30f;
                    m8 = fmaxf(m8, vals[g2][j]);
                }
                m8 = fmaxf(m8, __shfl_xor(m8, 16));
                m8 = fmaxf(m8, __shfl_xor(m8, 32));
                float ex[8]; float s8 = 0.0f;
                #pragma unroll
                for (int j = 0; j < 8; ++j) { ex[j] = __expf(vals[g2][j] - m8); s8 += ex[j]; }
                s8 += __shfl_xor(s8, 16); s8 += __shfl_xor(s8, 32);
                const float inv = __fdividef(1.0f, s8);
                if (lm == 0) {
                    #pragma unroll
                    for (int j = 0; j < 8; ++j) {
                        const int kk = (j >> 2) * 16 + kkb + (j & 3);
                        s_attn[g2][head][kk] = ex[j] * inv;
                    }
                }
            }
        } else {
            const int cc = cb - 128;         // V col block in [0,128)
            #pragma unroll
            for (int r = 0; r < 4; ++r)
                #pragma unroll
                for (int c = 0; c < 2; ++c)
                    #pragma unroll
                    for (int e = 0; e < 4; ++e)
                        u.v[r * 16 + lg * 4 + e][cc + c * 16 + lm] = f2bf(acc[r][c][e]);
        }
    }
    __syncthreads();

    // ---------------- phase 3: ctx = attn @ v (from LDS V) --------------------
    {
        const int g = tid >> 7, d = tid & 127, h = d >> 5;
        float acc = 0.0f;
        #pragma unroll
        for (int kk = 0; kk < KN; ++kk)
            acc = fmaf(s_attn[g][h][kk], bf2f(u.v[g * 32 + kk][d]), acc);
        s_ctx[g][d] = acc;
    }
    __syncthreads();

    // ---------------- phase 4: out projection, x2, layernorm ------------------
    {
        const int g = tid >> 7, j = tid & 127;
        float acc2 = bo[j];
        const float4* w4 = (const float4*)(Wo + (size_t)j * HIDN);
        const float4* x4 = (const float4*)s_ctx[g];
        #pragma unroll
        for (int c = 0; c < HIDN / 4; ++c) {
            float4 wv = w4[c]; float4 x = x4[c];
            acc2 = fmaf(wv.x, x.x, acc2); acc2 = fmaf(wv.y, x.y, acc2);
            acc2 = fmaf(wv.z, x.z, acc2); acc2 = fmaf(wv.w, x.w, acc2);
        }
        float o = acc2 * 2.0f;
        float s = o, ss = o * o;
        #pragma unroll
        for (int off = 32; off; off >>= 1) {
            s  += __shfl_xor(s, off);
            ss += __shfl_xor(ss, off);
        }
        if (lane == 0) { s_red[w][0] = s; s_red[w][1] = ss; }
        __syncthreads();
        float fs  = s_red[g * 2][0] + s_red[g * 2 + 1][0];
        float fss = s_red[g * 2][1] + s_red[g * 2 + 1][1];
        float mu  = fs * (1.0f / HIDN);
        float var = fss * (1.0f / HIDN) - mu * mu;
        float y = (o - mu) * rsqrtf(var + 1e-5f) * ln_g[j] + ln_b[j];
        out[(size_t)(n0 + g) * HIDN + j] = y;
    }
}

extern "C" void kernel_launch(void* const* d_in, const int* in_sizes, int n_in,
                              void* d_out, int out_size, void* d_ws, size_t ws_size,
                              hipStream_t stream) {
    const float* src    = (const float*)d_in[0];
    const float* dest   = (const float*)d_in[1];
    const int*   adj    = (const int*)  d_in[2];
    const int*   mask   = (const int*)  d_in[3];
    const float* edges  = (const float*)d_in[4];
    const float* W_src  = (const float*)d_in[5];
    const float* b_src  = (const float*)d_in[6];
    const float* W_dest = (const float*)d_in[7];
    const float* b_dest = (const float*)d_in[8];
    const float* Wqkv   = (const float*)d_in[9];
    const float* bqkv   = (const float*)d_in[10];
    const float* Wo     = (const float*)d_in[11];
    const float* bo     = (const float*)d_in[12];
    const float* ln_g   = (const float*)d_in[13];
    const float* ln_b   = (const float*)d_in[14];
    float* outp = (float*)d_out;

    unsigned short* ws = (unsigned short*)d_ws;
    const int prep_elems = 128 * XDP + 256 * HIDN;           // 45056
    prep_weights<<<prep_elems / 256, 256, 0, stream>>>(W_src, Wqkv, ws);

    fused_gat_mfma<<<N_DEST / G, 256, 0, stream>>>(
        src, dest, adj, mask, edges, b_src, W_dest, b_dest,
        Wqkv, bqkv, Wo, bo, ln_g, ln_b,
        ws, ws + 128 * XDP, outp);
}

// Round 6
// 424.846 us; speedup vs baseline: 1.3190x; 1.3190x over previous
//
#include <hip/hip_runtime.h>
#include <hip/hip_bf16.h>
#include <math.h>

// Problem constants
#define N_DEST 16000   // B * D_CNT
#define KN     32      // neighbors per dest
#define HIDN   128
#define NH     4
#define SRCD   64
#define EDGED  16
#define XD     80
#define XDP    96      // XD padded to 3 K-tiles of 32
#define SNP    136     // s_sin row stride (128 + 8 pad)
#define WPB    4       // waves (= dest nodes) per block

// bf16 weight workspace layout (shorts)
#define WSB_OFF 0        // W_src padded 128 x 96
#define WKV_OFF 12288    // Wqkv rows 128..383 (K then V), 256 x 128
#define WDB_OFF 45056    // W_dest 128 x 64
#define WQB_OFF 53248    // Wqkv rows 0..127 (Q), 128 x 128
#define WOB_OFF 69632    // Wo 128 x 128
#define PREP_TOT 86016

typedef __attribute__((ext_vector_type(8))) short frag8;   // 8 bf16 (4 VGPR)
typedef __attribute__((ext_vector_type(4))) float f32x4;

// tanh-form GELU (|diff vs exact erf-gelu| <= ~2e-3)
__device__ __forceinline__ float gelu_tanh(float x) {
    float t = x * x;
    float m = fmaf(t, -0.07135481627f, -1.5957691216f);
    float e = __expf(x * m);
    return __fdividef(x, 1.0f + e);
}
__device__ __forceinline__ unsigned short f2bf(float f) {
    __hip_bfloat16 h = __float2bfloat16(f);
    union { __hip_bfloat16 h; unsigned short u; } c; c.h = h; return c.u;
}
__device__ __forceinline__ unsigned int pk2bf(float x, float y) {
    __hip_bfloat162 h2 = __float22bfloat162_rn(make_float2(x, y));
    union { __hip_bfloat162 h; unsigned int u; } c; c.h = h2; return c.u;
}
__device__ __forceinline__ float bflo(unsigned int u) {
    union { unsigned int u; float f; } c; c.u = u << 16; return c.f;
}
__device__ __forceinline__ float bfhi(unsigned int u) {
    union { unsigned int u; float f; } c; c.u = u & 0xFFFF0000u; return c.f;
}
__device__ __forceinline__ float dot8(uint4 w, float4 x0, float4 x1, float acc) {
    acc = fmaf(bflo(w.x), x0.x, acc); acc = fmaf(bfhi(w.x), x0.y, acc);
    acc = fmaf(bflo(w.y), x0.z, acc); acc = fmaf(bfhi(w.y), x0.w, acc);
    acc = fmaf(bflo(w.z), x1.x, acc); acc = fmaf(bfhi(w.z), x1.y, acc);
    acc = fmaf(bflo(w.w), x1.z, acc); acc = fmaf(bfhi(w.w), x1.w, acc);
    return acc;
}
__device__ __forceinline__ frag8 pack_frag(float4 f0, float4 f1) {
    union { frag8 f; uint4 u; } c;
    c.u.x = pk2bf(f0.x, f0.y); c.u.y = pk2bf(f0.z, f0.w);
    c.u.z = pk2bf(f1.x, f1.y); c.u.w = pk2bf(f1.z, f1.w);
    return c.f;
}
__device__ __forceinline__ frag8 zero_frag() {
    union { frag8 f; uint4 u; } c;
    c.u = make_uint4(0u, 0u, 0u, 0u);
    return c.f;
}

// ---- prep: convert all weight matrices to bf16 in d_ws ----
__global__ void prep_weights(const float* __restrict__ W_src,
                             const float* __restrict__ W_dest,
                             const float* __restrict__ Wqkv,
                             const float* __restrict__ Wo,
                             unsigned short* __restrict__ ws) {
    int i = blockIdx.x * 256 + threadIdx.x;
    if (i < WKV_OFF) {                       // W_src 128 x 96 (pad K 80->96)
        int r = i / XDP, c = i - r * XDP;
        ws[i] = f2bf(c < XD ? W_src[r * XD + c] : 0.0f);
    } else if (i < WDB_OFF) {                // Wqkv K/V rows
        int j = i - WKV_OFF;
        ws[i] = f2bf(Wqkv[128 * HIDN + j]);
    } else if (i < WQB_OFF) {                // W_dest
        ws[i] = f2bf(W_dest[i - WDB_OFF]);
    } else if (i < WOB_OFF) {                // Wqkv Q rows
        ws[i] = f2bf(Wqkv[i - WQB_OFF]);
    } else if (i < PREP_TOT) {               // Wo
        ws[i] = f2bf(Wo[i - WOB_OFF]);
    }
}

__global__ __launch_bounds__(256, 3) void fused_gat_wave(
    const float* __restrict__ src,    // (16000, 64)
    const float* __restrict__ dest,   // (16000, 64)
    const int*   __restrict__ adj,    // (32, 16000)
    const int*   __restrict__ mask,   // (16000, 32)
    const float* __restrict__ edges,  // (32, 16000, 16)
    const float* __restrict__ b_src,
    const float* __restrict__ b_dest,
    const float* __restrict__ bqkv,
    const float* __restrict__ bo,
    const float* __restrict__ ln_g,
    const float* __restrict__ ln_b,
    const unsigned short* __restrict__ ws,   // bf16 weights
    float* __restrict__ out)
{
    const int tid  = threadIdx.x;
    const int wv   = tid >> 6;        // wave id 0..3
    const int lane = tid & 63;
    const int lg   = lane >> 4;       // 0..3
    const int lm   = lane & 15;       // 0..15
    const int n    = blockIdx.x * WPB + wv;   // this wave's dest node

    const unsigned short* Wsb = ws + WSB_OFF;
    const unsigned short* Wkv = ws + WKV_OFF;
    const unsigned short* Wdb = ws + WDB_OFF;
    const unsigned short* Wqb = ws + WQB_OFF;
    const unsigned short* Wob = ws + WOB_OFF;

    // per-wave LDS slices; no cross-wave sharing -> zero __syncthreads
    __shared__ __align__(16) unsigned short s_sin[WPB][KN][SNP];  // 34.8 KB
    __shared__ __align__(16) float s_dest[WPB][HIDN];
    __shared__ __align__(16) float s_q[WPB][HIDN];
    __shared__ __align__(16) float s_attn[WPB][NH][KN];
    __shared__ __align__(16) float s_ctx[WPB][HIDN];

    // ---- hoisted per-lane loads ----
    const int a0 = adj[lm * N_DEST + n];          // src row for kk = lm
    const int a1 = adj[(lm + 16) * N_DEST + n];   // src row for kk = lm+16
    int mv = (lane < KN) ? mask[n * KN + lane] : 0;
    const unsigned mw = (unsigned)__ballot(mv != 0);   // bit kk => masked out

    // ---------------- phase A: dest_in (gelu) ----------------
    {
        const float* drow = dest + (size_t)n * SRCD;   // wave-uniform
        float da0 = b_dest[lane], da1 = b_dest[lane + 64];
        #pragma unroll
        for (int c = 0; c < 8; ++c) {
            float4 x0 = *(const float4*)(drow + c * 8);
            float4 x1 = *(const float4*)(drow + c * 8 + 4);
            uint4 w0 = *(const uint4*)(Wdb + (size_t)lane * SRCD + c * 8);
            uint4 w1 = *(const uint4*)(Wdb + (size_t)(lane + 64) * SRCD + c * 8);
            da0 = dot8(w0, x0, x1, da0);
            da1 = dot8(w1, x0, x1, da1);
        }
        s_dest[wv][lane]      = gelu_tanh(da0);
        s_dest[wv][lane + 64] = gelu_tanh(da1);
    }
    __builtin_amdgcn_wave_barrier();

    // ---------------- phase B: q projection ----------------
    {
        float qa0 = bqkv[lane], qa1 = bqkv[lane + 64];
        #pragma unroll
        for (int c = 0; c < 16; ++c) {
            float4 x0 = *(const float4*)&s_dest[wv][c * 8];
            float4 x1 = *(const float4*)&s_dest[wv][c * 8 + 4];
            uint4 w0 = *(const uint4*)(Wqb + (size_t)lane * HIDN + c * 8);
            uint4 w1 = *(const uint4*)(Wqb + (size_t)(lane + 64) * HIDN + c * 8);
            qa0 = dot8(w0, x0, x1, qa0);
            qa1 = dot8(w1, x0, x1, qa1);
        }
        s_q[wv][lane]      = qa0 * 0.17677669529663688110f;  // 1/sqrt(32)
        s_q[wv][lane + 64] = qa1 * 0.17677669529663688110f;
    }
    __builtin_amdgcn_wave_barrier();

    // ---------------- phase C: GEMM-D (32 x 96 @ 96 x 128) -> gelu -> s_sin ----
    {
        f32x4 accD[2][8];
        #pragma unroll
        for (int ct = 0; ct < 8; ++ct) {
            float bias = b_src[ct * 16 + lm];
            accD[0][ct] = (f32x4){bias, bias, bias, bias};
            accD[1][ct] = (f32x4){bias, bias, bias, bias};
        }
        #pragma unroll
        for (int kt = 0; kt < 3; ++kt) {
            frag8 a[2];
            if (kt < 2) {
                const int c0 = kt * 32 + lg * 8;
                if (a0) {
                    const float4* p = (const float4*)(src + (size_t)(a0 - 1) * SRCD + c0);
                    a[0] = pack_frag(p[0], p[1]);
                } else a[0] = zero_frag();
                if (a1) {
                    const float4* p = (const float4*)(src + (size_t)(a1 - 1) * SRCD + c0);
                    a[1] = pack_frag(p[0], p[1]);
                } else a[1] = zero_frag();
            } else {
                if (lg < 2) {   // x-cols 64..79 = edges 0..15
                    const float4* p0 = (const float4*)(edges + ((size_t)lm * N_DEST + n) * EDGED + lg * 8);
                    const float4* p1 = (const float4*)(edges + ((size_t)(lm + 16) * N_DEST + n) * EDGED + lg * 8);
                    a[0] = pack_frag(p0[0], p0[1]);
                    a[1] = pack_frag(p1[0], p1[1]);
                } else {        // x-cols 80..95 = zero pad
                    a[0] = zero_frag(); a[1] = zero_frag();
                }
            }
            #pragma unroll
            for (int ct = 0; ct < 8; ++ct) {
                frag8 b = *(const frag8*)(Wsb + (size_t)(ct * 16 + lm) * XDP + kt * 32 + lg * 8);
                accD[0][ct] = __builtin_amdgcn_mfma_f32_16x16x32_bf16(a[0], b, accD[0][ct], 0, 0, 0);
                accD[1][ct] = __builtin_amdgcn_mfma_f32_16x16x32_bf16(a[1], b, accD[1][ct], 0, 0, 0);
            }
        }
        #pragma unroll
        for (int r = 0; r < 2; ++r)
            #pragma unroll
            for (int ct = 0; ct < 8; ++ct)
                #pragma unroll
                for (int e = 0; e < 4; ++e)
                    s_sin[wv][r * 16 + lg * 4 + e][ct * 16 + lm] =
                        f2bf(gelu_tanh(accD[r][ct][e]));
    }
    __builtin_amdgcn_wave_barrier();

    // ---------------- phase D: GEMM-E in 4 chunks of 64 cols -------------------
    // chunks 0,1 = K features (heads 2c, 2c+1): scores -> masked softmax -> s_attn
    // chunks 2,3 = V features: PV from accumulators -> s_ctx
    #pragma unroll 1
    for (int ch = 0; ch < 4; ++ch) {
        f32x4 acc[2][4];
        #pragma unroll
        for (int ct = 0; ct < 4; ++ct) {
            float bias = bqkv[128 + ch * 64 + ct * 16 + lm];
            acc[0][ct] = (f32x4){bias, bias, bias, bias};
            acc[1][ct] = (f32x4){bias, bias, bias, bias};
        }
        #pragma unroll
        for (int kt = 0; kt < 4; ++kt) {
            frag8 a0f = *(const frag8*)&s_sin[wv][lm][kt * 32 + lg * 8];
            frag8 a1f = *(const frag8*)&s_sin[wv][16 + lm][kt * 32 + lg * 8];
            #pragma unroll
            for (int ct = 0; ct < 4; ++ct) {
                frag8 b = *(const frag8*)(Wkv + (size_t)(ch * 64 + ct * 16 + lm) * HIDN + kt * 32 + lg * 8);
                acc[0][ct] = __builtin_amdgcn_mfma_f32_16x16x32_bf16(a0f, b, acc[0][ct], 0, 0, 0);
                acc[1][ct] = __builtin_amdgcn_mfma_f32_16x16x32_bf16(a1f, b, acc[1][ct], 0, 0, 0);
            }
        }
        if (ch < 2) {
            // scores + masked softmax for heads 2ch, 2ch+1
            #pragma unroll
            for (int hp = 0; hp < 2; ++hp) {
                const int head = ch * 2 + hp;
                float q0 = s_q[wv][ch * 64 + hp * 32 + lm];
                float q1 = s_q[wv][ch * 64 + hp * 32 + 16 + lm];
                float vals[8];    // j = r*4+e -> kk = 16r + lg*4 + e
                #pragma unroll
                for (int r = 0; r < 2; ++r)
                    #pragma unroll
                    for (int e = 0; e < 4; ++e) {
                        float v = acc[r][2 * hp][e] * q0 + acc[r][2 * hp + 1][e] * q1;
                        v += __shfl_xor(v, 1); v += __shfl_xor(v, 2);
                        v += __shfl_xor(v, 4); v += __shfl_xor(v, 8);
                        vals[r * 4 + e] = v;
                    }
                float m8 = -1e30f;
                #pragma unroll
                for (int j = 0; j < 8; ++j) {
                    const int kk = (j >> 2) * 16 + lg * 4 + (j & 3);
                    if ((mw >> kk) & 1u) vals[j] = -1e30f;
                    m8 = fmaxf(m8, vals[j]);
                }
                m8 = fmaxf(m8, __shfl_xor(m8, 16));
                m8 = fmaxf(m8, __shfl_xor(m8, 32));
                float ex[8], s8 = 0.0f;
                #pragma unroll
                for (int j = 0; j < 8; ++j) { ex[j] = __expf(vals[j] - m8); s8 += ex[j]; }
                s8 += __shfl_xor(s8, 16); s8 += __shfl_xor(s8, 32);
                const float inv = __fdividef(1.0f, s8);
                if (lm == 0) {
                    *(float4*)&s_attn[wv][head][lg * 4] =
                        make_float4(ex[0] * inv, ex[1] * inv, ex[2] * inv, ex[3] * inv);
                    *(float4*)&s_attn[wv][head][16 + lg * 4] =
                        make_float4(ex[4] * inv, ex[5] * inv, ex[6] * inv, ex[7] * inv);
                }
            }
        } else {
            // PV: ctx[d] = sum_kk attn[h][kk] * V[kk][d]
            const int hb = (ch - 2) * 2;
            float4 at[2][2];    // [hp][r]
            #pragma unroll
            for (int hp = 0; hp < 2; ++hp)
                #pragma unroll
                for (int r = 0; r < 2; ++r)
                    at[hp][r] = *(const float4*)&s_attn[wv][hb + hp][r * 16 + lg * 4];
            #pragma unroll
            for (int ct = 0; ct < 4; ++ct) {
                const int hp = ct >> 1;
                float v = 0.0f;
                #pragma unroll
                for (int r = 0; r < 2; ++r) {
                    v = fmaf(at[hp][r].x, acc[r][ct][0], v);
                    v = fmaf(at[hp][r].y, acc[r][ct][1], v);
                    v = fmaf(at[hp][r].z, acc[r][ct][2], v);
                    v = fmaf(at[hp][r].w, acc[r][ct][3], v);
                }
                v += __shfl_xor(v, 16); v += __shfl_xor(v, 32);
                if (lg == 0) s_ctx[wv][(ch - 2) * 64 + ct * 16 + lm] = v;
            }
        }
    }
    __builtin_amdgcn_wave_barrier();

    // ---------------- phase E: out projection, x2, layernorm ------------------
    {
        float oa0 = bo[lane], oa1 = bo[lane + 64];
        #pragma unroll
        for (int c = 0; c < 16; ++c) {
            float4 x0 = *(const float4*)&s_ctx[wv][c * 8];
            float4 x1 = *(const float4*)&s_ctx[wv][c * 8 + 4];
            uint4 w0 = *(const uint4*)(Wob + (size_t)lane * HIDN + c * 8);
            uint4 w1 = *(const uint4*)(Wob + (size_t)(lane + 64) * HIDN + c * 8);
            oa0 = dot8(w0, x0, x1, oa0);
            oa1 = dot8(w1, x0, x1, oa1);
        }
        float o0 = oa0 * 2.0f, o1 = oa1 * 2.0f;
        float s = o0 + o1, ss = o0 * o0 + o1 * o1;
        #pragma unroll
        for (int off = 1; off < 64; off <<= 1) {
            s  += __shfl_xor(s, off);
            ss += __shfl_xor(ss, off);
        }
        float mu  = s * (1.0f / HIDN);
        float var = ss * (1.0f / HIDN) - mu * mu;
        float rs  = rsqrtf(var + 1e-5f);
        out[(size_t)n * HIDN + lane]      = (o0 - mu) * rs * ln_g[lane] + ln_b[lane];
        out[(size_t)n * HIDN + lane + 64] = (o1 - mu) * rs * ln_g[lane + 64] + ln_b[lane + 64];
    }
}

extern "C" void kernel_launch(void* const* d_in, const int* in_sizes, int n_in,
                              void* d_out, int out_size, void* d_ws, size_t ws_size,
                              hipStream_t stream) {
    const float* src    = (const float*)d_in[0];
    const float* dest   = (const float*)d_in[1];
    const int*   adj    = (const int*)  d_in[2];
    const int*   mask   = (const int*)  d_in[3];
    const float* edges  = (const float*)d_in[4];
    const float* W_src  = (const float*)d_in[5];
    const float* b_src  = (const float*)d_in[6];
    const float* W_dest = (const float*)d_in[7];
    const float* b_dest = (const float*)d_in[8];
    const float* Wqkv   = (const float*)d_in[9];
    const float* bqkv   = (const float*)d_in[10];
    const float* Wo     = (const float*)d_in[11];
    const float* bo     = (const float*)d_in[12];
    const float* ln_g   = (const float*)d_in[13];
    const float* ln_b   = (const float*)d_in[14];
    float* outp = (float*)d_out;

    unsigned short* ws = (unsigned short*)d_ws;
    prep_weights<<<PREP_TOT / 256, 256, 0, stream>>>(W_src, W_dest, Wqkv, Wo, ws);

    fused_gat_wave<<<N_DEST / WPB, 256, 0, stream>>>(
        src, dest, adj, mask, edges, b_src, b_dest, bqkv, bo, ln_g, ln_b,
        ws, outp);
}